// Round 5
// baseline (656.822 us; speedup 1.0000x reference)
//
#include <hip/hip_runtime.h>
#include <hip/hip_bf16.h>

#define HID 128

typedef __attribute__((ext_vector_type(8))) short short8;
typedef __attribute__((ext_vector_type(4))) float f32x4;

__device__ __forceinline__ unsigned short f2bf(float f) {
    unsigned int u = __builtin_bit_cast(unsigned int, f);
    u += 0x7FFFu + ((u >> 16) & 1u);            // round-to-nearest-even
    return (unsigned short)(u >> 16);
}
__device__ __forceinline__ float bf2f(unsigned short h) {
    unsigned int u = ((unsigned int)h) << 16;
    return __builtin_bit_cast(float, u);
}

// ---------------- prep: x -> bf16 ----------------
__global__ void prep_x(const float4* __restrict__ x4, unsigned short* __restrict__ xb, int n4) {
    int t = blockIdx.x * 256 + threadIdx.x;
    if (t >= n4) return;
    float4 v = x4[t];
    union { unsigned short u[4]; uint2 d; } p;
    p.u[0] = f2bf(v.x); p.u[1] = f2bf(v.y); p.u[2] = f2bf(v.z); p.u[3] = f2bf(v.w);
    *(uint2*)(xb + (size_t)t * 4) = p.d;
}

// ---------------- prep: W[k][128] -> fragment order Wf[ks][nt][lane][j] ----------------
__global__ void prep_w(const float* __restrict__ W, unsigned short* __restrict__ Wf, int nks) {
    int t = blockIdx.x * 256 + threadIdx.x;
    if (t >= nks * 8 * 64) return;
    int lane = t & 63, nt = (t >> 6) & 7, ks = t >> 9;
    int kb  = ks * 32 + ((lane >> 4) << 3);
    int col = (nt << 4) + (lane & 15);
    union { unsigned short u[8]; uint4 q; } p;
    #pragma unroll
    for (int j = 0; j < 8; ++j) p.u[j] = f2bf(W[(size_t)(kb + j) * 128 + col]);
    *(uint4*)(Wf + (size_t)t * 8) = p.q;
}

// hi/lo split version for near-fp32 node GEMMs
__global__ void prep_w_split(const float* __restrict__ W,
                             unsigned short* __restrict__ Wh,
                             unsigned short* __restrict__ Wl, int nks) {
    int t = blockIdx.x * 256 + threadIdx.x;
    if (t >= nks * 8 * 64) return;
    int lane = t & 63, nt = (t >> 6) & 7, ks = t >> 9;
    int kb  = ks * 32 + ((lane >> 4) << 3);
    int col = (nt << 4) + (lane & 15);
    union { unsigned short u[8]; uint4 q; } ph, pl;
    #pragma unroll
    for (int j = 0; j < 8; ++j) {
        float w = W[(size_t)(kb + j) * 128 + col];
        unsigned short h = f2bf(w);
        ph.u[j] = h;
        pl.u[j] = f2bf(w - bf2f(h));
    }
    *(uint4*)(Wh + (size_t)t * 8) = ph.q;
    *(uint4*)(Wl + (size_t)t * 8) = pl.q;
}

// ---------------- Edge kernel: barrier-free wave-private tiles, M=16/wave ----------------
// K-split staging into a 4 KB per-wave LDS buffer; high occupancy hides gather/B-load latency.
__global__ __launch_bounds__(256, 6)
void edge_mfma(const unsigned short* __restrict__ xb,   // [N][128] bf16
               const int* __restrict__ ei,              // [2][E]
               const float* __restrict__ ea,            // [E][3]
               const unsigned short* __restrict__ W1f,  // [8][8][64][8] bf16
               const unsigned short* __restrict__ W2f,  // [4][8][64][8] bf16
               const float* __restrict__ W1tail,        // [3][128] fp32
               const float* __restrict__ bm1,
               const float* __restrict__ bm2,
               float* __restrict__ agg,
               int E)
{
    __shared__ alignas(16) char As[4][4096];   // per-wave: 16 rows x 256 B, XOR-swizzled

    const int tid  = threadIdx.x;
    const int lane = tid & 63;
    const int wid  = tid >> 6;
    const int e0   = blockIdx.x * 64 + wid * 16;
    if (e0 >= E) return;                       // no barriers in this kernel -> safe

    char* Aw = As[wid];
    const int crow  = lane >> 4;               // staging: 4 rows per iter
    const int cbyte = (lane & 15) * 16;        // staging: 16 B chunk within 256 B row

    const int arow  = lane & 15;               // MFMA A row / C col
    const int abyte = (lane >> 4) * 16;        // MFMA A k-subgroup byte
    const int g4    = lane >> 4;

    f32x4 acc[8];
    #pragma unroll
    for (int i = 0; i < 8; ++i) acc[i] = (f32x4)0.f;

    // ---- stage 16 src rows (coalesced: 16 lanes = one 256 B row) ----
    #pragma unroll
    for (int it = 0; it < 4; ++it) {
        int r = it * 4 + crow;
        int e = e0 + r; int ec = (e < E) ? e : (E - 1);
        int node = ei[ec];
        uint4 v = *(const uint4*)(xb + (size_t)node * 128 + (cbyte >> 1));
        *(uint4*)(Aw + r * 256 + (cbyte ^ (r << 4))) = v;
    }
    asm volatile("s_waitcnt lgkmcnt(0)" ::: "memory");

    // ---- GEMM1 ks 0..3 (src half of K) ----
    #pragma unroll
    for (int ks = 0; ks < 4; ++ks) {
        int cb = ks * 64 + abyte;
        short8 a0 = *(const short8*)(Aw + arow * 256 + (cb ^ (arow << 4)));
        #pragma unroll
        for (int nt = 0; nt < 8; ++nt) {
            short8 bf = *(const short8*)(W1f + (size_t)((ks * 8 + nt) * 64 + lane) * 8);
            acc[nt] = __builtin_amdgcn_mfma_f32_16x16x32_bf16(a0, bf, acc[nt], 0, 0, 0);
        }
    }
    // ensure all src-half LDS reads complete before overwriting (WAR)
    asm volatile("s_waitcnt lgkmcnt(0)" ::: "memory");

    // ---- stage 16 dst rows over the same buffer ----
    #pragma unroll
    for (int it = 0; it < 4; ++it) {
        int r = it * 4 + crow;
        int e = e0 + r; int ec = (e < E) ? e : (E - 1);
        int node = ei[E + ec];
        uint4 v = *(const uint4*)(xb + (size_t)node * 128 + (cbyte >> 1));
        *(uint4*)(Aw + r * 256 + (cbyte ^ (r << 4))) = v;
    }
    asm volatile("s_waitcnt lgkmcnt(0)" ::: "memory");

    // ---- GEMM1 ks 4..7 (dst half of K) ----
    #pragma unroll
    for (int ks = 0; ks < 4; ++ks) {
        int cb = ks * 64 + abyte;
        short8 a0 = *(const short8*)(Aw + arow * 256 + (cb ^ (arow << 4)));
        #pragma unroll
        for (int nt = 0; nt < 8; ++nt) {
            short8 bf = *(const short8*)(W1f + (size_t)(((ks + 4) * 8 + nt) * 64 + lane) * 8);
            acc[nt] = __builtin_amdgcn_mfma_f32_16x16x32_bf16(a0, bf, acc[nt], 0, 0, 0);
        }
    }
    // all dst-half reads done before H overwrites the buffer
    asm volatile("s_waitcnt lgkmcnt(0)" ::: "memory");

    // ---- epilogue 1: + edge_attr (exact fp32) + bias, relu, store H bf16 swizzled ----
    // rows owned by this lane: el = g4*4 + r  (same for all 16 lanes of a group -> broadcast loads)
    float eav[4][3];
    #pragma unroll
    for (int r = 0; r < 4; ++r) {
        int e = e0 + g4 * 4 + r; int ec = (e < E) ? e : (E - 1);
        eav[r][0] = ea[(size_t)ec * 3 + 0];
        eav[r][1] = ea[(size_t)ec * 3 + 1];
        eav[r][2] = ea[(size_t)ec * 3 + 2];
    }
    #pragma unroll
    for (int nt = 0; nt < 8; ++nt) {
        int col = nt * 16 + arow;
        float w0 = W1tail[col], w1 = W1tail[128 + col], w2 = W1tail[256 + col];
        float b1 = bm1[col];
        #pragma unroll
        for (int r = 0; r < 4; ++r) {
            int el = g4 * 4 + r;
            float h = acc[nt][r] + b1;
            h = fmaf(eav[r][0], w0, h);
            h = fmaf(eav[r][1], w1, h);
            h = fmaf(eav[r][2], w2, h);
            h = fmaxf(h, 0.f);
            *(unsigned short*)(&Aw[el * 256 + ((col * 2) ^ (el << 4))]) = f2bf(h);
        }
    }
    asm volatile("s_waitcnt lgkmcnt(0)" ::: "memory");

    // ---- GEMM2: H[16,128]bf16 @ [128,128]bf16 ----
    #pragma unroll
    for (int i = 0; i < 8; ++i) acc[i] = (f32x4)0.f;
    #pragma unroll
    for (int ks = 0; ks < 4; ++ks) {
        int cb = ks * 64 + abyte;
        short8 a0 = *(const short8*)(Aw + arow * 256 + (cb ^ (arow << 4)));
        #pragma unroll
        for (int nt = 0; nt < 8; ++nt) {
            short8 bf = *(const short8*)(W2f + (size_t)((ks * 8 + nt) * 64 + lane) * 8);
            acc[nt] = __builtin_amdgcn_mfma_f32_16x16x32_bf16(a0, bf, acc[nt], 0, 0, 0);
        }
    }

    // ---- epilogue 2: + bias, atomic scatter-add into agg[dst] ----
    int dstr[4];
    #pragma unroll
    for (int r = 0; r < 4; ++r) {
        int e = e0 + g4 * 4 + r; int ec = (e < E) ? e : (E - 1);
        dstr[r] = ei[E + ec];
    }
    #pragma unroll
    for (int nt = 0; nt < 8; ++nt) {
        int col = nt * 16 + arow;
        float b2 = bm2[col];
        #pragma unroll
        for (int r = 0; r < 4; ++r) {
            int eg = e0 + g4 * 4 + r;
            if (eg < E)
                unsafeAtomicAdd(agg + (size_t)dstr[r] * 128 + col, acc[nt][r] + b2);
        }
    }
}

// ---------------- Node kernel: bf16 MFMA with hi/lo split (near-fp32) ----------------
__global__ __launch_bounds__(256, 3)
void node_mfma(const float* __restrict__ x,
               const float* __restrict__ agg,
               const unsigned short* __restrict__ WgH, const unsigned short* __restrict__ WgL,
               const unsigned short* __restrict__ Wu1H, const unsigned short* __restrict__ Wu1L,
               const unsigned short* __restrict__ Wu2H, const unsigned short* __restrict__ Wu2L,
               const float* __restrict__ bg, const float* __restrict__ bu1,
               const float* __restrict__ bu2,
               const float* __restrict__ gamma, const float* __restrict__ beta,
               float* __restrict__ out, int N)
{
    __shared__ alignas(16) char Hs[4][8192];   // per-wave u1 hi/lo packed: 16 rows x 512 B

    const int tid  = threadIdx.x;
    const int lane = tid & 63;
    const int wid  = tid >> 6;
    const int n0   = (blockIdx.x * 4 + wid) * 16;
    if (n0 >= N) return;

    const int arow = lane & 15;
    const int g4   = lane >> 4;

    int nr = n0 + arow; if (nr >= N) nr = N - 1;
    const float* px = x   + (size_t)nr * 128 + g4 * 8;
    const float* pa = agg + (size_t)nr * 128 + g4 * 8;

    // ---- build A-frags (hi/lo) for [x | agg], K = 256 ----
    short8 ah[8], al[8];
    #pragma unroll
    for (int ks = 0; ks < 8; ++ks) {
        const float* p = (ks < 4) ? (px + ks * 32) : (pa + (ks - 4) * 32);
        float4 v0 = *(const float4*)p;
        float4 v1 = *(const float4*)(p + 4);
        float v[8] = { v0.x, v0.y, v0.z, v0.w, v1.x, v1.y, v1.z, v1.w };
        #pragma unroll
        for (int j = 0; j < 8; ++j) {
            unsigned short h = f2bf(v[j]);
            ah[ks][j] = (short)h;
            al[ks][j] = (short)f2bf(v[j] - bf2f(h));
        }
    }

    // ---- gate GEMM (K=256, 3-pass split) ----
    f32x4 ga[8];
    #pragma unroll
    for (int i = 0; i < 8; ++i) ga[i] = (f32x4)0.f;
    #pragma unroll
    for (int ks = 0; ks < 8; ++ks) {
        #pragma unroll
        for (int nt = 0; nt < 8; ++nt) {
            size_t o = (size_t)((ks * 8 + nt) * 64 + lane) * 8;
            short8 bh = *(const short8*)(WgH + o);
            short8 bl = *(const short8*)(WgL + o);
            ga[nt] = __builtin_amdgcn_mfma_f32_16x16x32_bf16(ah[ks], bh, ga[nt], 0, 0, 0);
            ga[nt] = __builtin_amdgcn_mfma_f32_16x16x32_bf16(al[ks], bh, ga[nt], 0, 0, 0);
            ga[nt] = __builtin_amdgcn_mfma_f32_16x16x32_bf16(ah[ks], bl, ga[nt], 0, 0, 0);
        }
    }

    // ---- u1 GEMM (K=256, 3-pass split) ----
    f32x4 ua[8];
    #pragma unroll
    for (int i = 0; i < 8; ++i) ua[i] = (f32x4)0.f;
    #pragma unroll
    for (int ks = 0; ks < 8; ++ks) {
        #pragma unroll
        for (int nt = 0; nt < 8; ++nt) {
            size_t o = (size_t)((ks * 8 + nt) * 64 + lane) * 8;
            short8 bh = *(const short8*)(Wu1H + o);
            short8 bl = *(const short8*)(Wu1L + o);
            ua[nt] = __builtin_amdgcn_mfma_f32_16x16x32_bf16(ah[ks], bh, ua[nt], 0, 0, 0);
            ua[nt] = __builtin_amdgcn_mfma_f32_16x16x32_bf16(al[ks], bh, ua[nt], 0, 0, 0);
            ua[nt] = __builtin_amdgcn_mfma_f32_16x16x32_bf16(ah[ks], bl, ua[nt], 0, 0, 0);
        }
    }

    // relu + bias, split hi/lo, pack (hi|lo<<16) into wave-private LDS (transpose)
    #pragma unroll
    for (int nt = 0; nt < 8; ++nt) {
        int col = nt * 16 + arow;
        float b1 = bu1[col];
        #pragma unroll
        for (int r = 0; r < 4; ++r) {
            int row = g4 * 4 + r;
            float u = fmaxf(ua[nt][r] + b1, 0.f);
            unsigned short h = f2bf(u);
            unsigned short l = f2bf(u - bf2f(h));
            unsigned int pk = (unsigned int)h | ((unsigned int)l << 16);
            *(unsigned int*)(&Hs[wid][row * 512 + ((col * 4) ^ ((row & 15) << 4))]) = pk;
        }
    }

    // ---- gate finalize: sigmoid ----
    #pragma unroll
    for (int nt = 0; nt < 8; ++nt) {
        int col = nt * 16 + arow;
        float b = bg[col];
        #pragma unroll
        for (int r = 0; r < 4; ++r)
            ga[nt][r] = 1.f / (1.f + expf(-(ga[nt][r] + b)));
    }
    __syncthreads();

    // ---- u2 GEMM (K=128, 3-pass split), A from LDS ----
    f32x4 u2[8];
    #pragma unroll
    for (int i = 0; i < 8; ++i) u2[i] = (f32x4)0.f;
    #pragma unroll
    for (int ks = 0; ks < 4; ++ks) {
        int b0 = ks * 128 + g4 * 32;
        unsigned int q0[4], q1[4];
        *(uint4*)q0 = *(const uint4*)(&Hs[wid][arow * 512 + ( b0       ^ (arow << 4))]);
        *(uint4*)q1 = *(const uint4*)(&Hs[wid][arow * 512 + ((b0 + 16) ^ (arow << 4))]);
        short8 a2h, a2l;
        #pragma unroll
        for (int j = 0; j < 4; ++j) {
            a2h[j]     = (short)(q0[j] & 0xffff);
            a2l[j]     = (short)(q0[j] >> 16);
            a2h[4 + j] = (short)(q1[j] & 0xffff);
            a2l[4 + j] = (short)(q1[j] >> 16);
        }
        #pragma unroll
        for (int nt = 0; nt < 8; ++nt) {
            size_t o = (size_t)((ks * 8 + nt) * 64 + lane) * 8;
            short8 bh = *(const short8*)(Wu2H + o);
            short8 bl = *(const short8*)(Wu2L + o);
            u2[nt] = __builtin_amdgcn_mfma_f32_16x16x32_bf16(a2h, bh, u2[nt], 0, 0, 0);
            u2[nt] = __builtin_amdgcn_mfma_f32_16x16x32_bf16(a2l, bh, u2[nt], 0, 0, 0);
            u2[nt] = __builtin_amdgcn_mfma_f32_16x16x32_bf16(a2h, bl, u2[nt], 0, 0, 0);
        }
    }

    // ---- epilogue: gating + LayerNorm + store ----
    float s[4]  = {0.f, 0.f, 0.f, 0.f};
    float ss[4] = {0.f, 0.f, 0.f, 0.f};
    #pragma unroll
    for (int nt = 0; nt < 8; ++nt) {
        int col = nt * 16 + arow;
        float b2 = bu2[col];
        #pragma unroll
        for (int r = 0; r < 4; ++r) {
            int node = n0 + g4 * 4 + r;
            float xv = x[(size_t)node * 128 + col];
            float g  = ga[nt][r];
            float o  = g * (u2[nt][r] + b2) + (1.f - g) * xv;
            u2[nt][r] = o;
            s[r]  += o;
            ss[r] += o * o;
        }
    }
    #pragma unroll
    for (int off = 8; off >= 1; off >>= 1) {
        #pragma unroll
        for (int r = 0; r < 4; ++r) {
            s[r]  += __shfl_xor(s[r],  off);
            ss[r] += __shfl_xor(ss[r], off);
        }
    }
    float mu[4], rstd[4];
    #pragma unroll
    for (int r = 0; r < 4; ++r) {
        mu[r] = s[r] * (1.f / 128.f);
        float var = ss[r] * (1.f / 128.f) - mu[r] * mu[r];
        rstd[r] = rsqrtf(var + 1e-5f);
    }
    #pragma unroll
    for (int nt = 0; nt < 8; ++nt) {
        int col = nt * 16 + arow;
        float gm = gamma[col], bt = beta[col];
        #pragma unroll
        for (int r = 0; r < 4; ++r) {
            int node = n0 + g4 * 4 + r;
            if (node < N)
                out[(size_t)node * 128 + col] = (u2[nt][r] - mu[r]) * rstd[r] * gm + bt;
        }
    }
}

extern "C" void kernel_launch(void* const* d_in, const int* in_sizes, int n_in,
                              void* d_out, int out_size, void* d_ws, size_t ws_size,
                              hipStream_t stream)
{
    const float* x    = (const float*)d_in[0];
    const int*   ei   = (const int*)  d_in[1];
    const float* ea   = (const float*)d_in[2];
    const float* Wm1  = (const float*)d_in[3];
    const float* bm1  = (const float*)d_in[4];
    const float* Wm2  = (const float*)d_in[5];
    const float* bm2  = (const float*)d_in[6];
    const float* Wg   = (const float*)d_in[7];
    const float* bg   = (const float*)d_in[8];
    const float* Wu1  = (const float*)d_in[9];
    const float* bu1  = (const float*)d_in[10];
    const float* Wu2  = (const float*)d_in[11];
    const float* bu2  = (const float*)d_in[12];
    const float* gmma = (const float*)d_in[13];
    const float* beta = (const float*)d_in[14];
    float* out = (float*)d_out;

    const int N = in_sizes[0] / HID;
    const int E = in_sizes[1] / 2;

    // workspace carve-up
    float*          agg  = (float*)d_ws;                             // N*128 f32
    unsigned short* xb   = (unsigned short*)(agg + (size_t)N * HID); // N*128 bf16
    unsigned short* W1f  = xb + (size_t)N * HID;                     // 32768
    unsigned short* W2f  = W1f + 32768;                              // 16384
    unsigned short* WgH  = W2f + 16384;
    unsigned short* WgL  = WgH + 32768;
    unsigned short* Wu1H = WgL + 32768;
    unsigned short* Wu1L = Wu1H + 32768;
    unsigned short* Wu2H = Wu1L + 32768;
    unsigned short* Wu2L = Wu2H + 16384;

    hipMemsetAsync(agg, 0, (size_t)N * HID * sizeof(float), stream);

    int n4 = N * HID / 4;
    prep_x<<<dim3((n4 + 255) / 256), dim3(256), 0, stream>>>((const float4*)x, xb, n4);
    prep_w<<<dim3(16), dim3(256), 0, stream>>>(Wm1, W1f, 8);
    prep_w<<<dim3(8),  dim3(256), 0, stream>>>(Wm2, W2f, 4);
    prep_w_split<<<dim3(16), dim3(256), 0, stream>>>(Wg,  WgH,  WgL,  8);
    prep_w_split<<<dim3(16), dim3(256), 0, stream>>>(Wu1, Wu1H, Wu1L, 8);
    prep_w_split<<<dim3(8),  dim3(256), 0, stream>>>(Wu2, Wu2H, Wu2L, 4);

    edge_mfma<<<dim3((E + 63) / 64), dim3(256), 0, stream>>>(
        xb, ei, ea, W1f, W2f, Wm1 + 256 * HID, bm1, bm2, agg, E);

    int ntiles = (N + 15) / 16;
    node_mfma<<<dim3((ntiles + 3) / 4), dim3(256), 0, stream>>>(
        x, agg, WgH, WgL, Wu1H, Wu1L, Wu2H, Wu2L,
        bg, bu1, bu2, gmma, beta, out, N);
}

// Round 6
// 473.948 us; speedup vs baseline: 1.3859x; 1.3859x over previous
//
#include <hip/hip_runtime.h>
#include <hip/hip_bf16.h>

#define HID 128

typedef __attribute__((ext_vector_type(8))) short short8;
typedef __attribute__((ext_vector_type(4))) float f32x4;

__device__ __forceinline__ unsigned short f2bf(float f) {
    unsigned int u = __builtin_bit_cast(unsigned int, f);
    u += 0x7FFFu + ((u >> 16) & 1u);            // round-to-nearest-even
    return (unsigned short)(u >> 16);
}
__device__ __forceinline__ float bf2f(unsigned short h) {
    unsigned int u = ((unsigned int)h) << 16;
    return __builtin_bit_cast(float, u);
}

// ---------------- prep: x -> bf16 ----------------
__global__ void prep_x(const float4* __restrict__ x4, unsigned short* __restrict__ xb, int n4) {
    int t = blockIdx.x * 256 + threadIdx.x;
    if (t >= n4) return;
    float4 v = x4[t];
    union { unsigned short u[4]; uint2 d; } p;
    p.u[0] = f2bf(v.x); p.u[1] = f2bf(v.y); p.u[2] = f2bf(v.z); p.u[3] = f2bf(v.w);
    *(uint2*)(xb + (size_t)t * 4) = p.d;
}

// ---------------- prep: W[k][128] -> fragment order Wf[ks][nt][lane][j] ----------------
__global__ void prep_w(const float* __restrict__ W, unsigned short* __restrict__ Wf, int nks) {
    int t = blockIdx.x * 256 + threadIdx.x;
    if (t >= nks * 8 * 64) return;
    int lane = t & 63, nt = (t >> 6) & 7, ks = t >> 9;
    int kb  = ks * 32 + ((lane >> 4) << 3);
    int col = (nt << 4) + (lane & 15);
    union { unsigned short u[8]; uint4 q; } p;
    #pragma unroll
    for (int j = 0; j < 8; ++j) p.u[j] = f2bf(W[(size_t)(kb + j) * 128 + col]);
    *(uint4*)(Wf + (size_t)t * 8) = p.q;
}

// hi/lo split version for near-fp32 node GEMMs
__global__ void prep_w_split(const float* __restrict__ W,
                             unsigned short* __restrict__ Wh,
                             unsigned short* __restrict__ Wl, int nks) {
    int t = blockIdx.x * 256 + threadIdx.x;
    if (t >= nks * 8 * 64) return;
    int lane = t & 63, nt = (t >> 6) & 7, ks = t >> 9;
    int kb  = ks * 32 + ((lane >> 4) << 3);
    int col = (nt << 4) + (lane & 15);
    union { unsigned short u[8]; uint4 q; } ph, pl;
    #pragma unroll
    for (int j = 0; j < 8; ++j) {
        float w = W[(size_t)(kb + j) * 128 + col];
        unsigned short h = f2bf(w);
        ph.u[j] = h;
        pl.u[j] = f2bf(w - bf2f(h));
    }
    *(uint4*)(Wh + (size_t)t * 8) = ph.q;
    *(uint4*)(Wl + (size_t)t * 8) = pl.q;
}

// ---------------- counting sort of edges by dst ----------------
__global__ void hist_k(const int* __restrict__ ei, unsigned* __restrict__ cnt, int E) {
    int e = blockIdx.x * 256 + threadIdx.x;
    if (e < E) atomicAdd(&cnt[ei[E + e]], 1u);
}

// single-block exclusive scan (N up to ~a few hundred k), 1024 threads
__global__ void scan_k(const unsigned* __restrict__ cnt, unsigned* __restrict__ cur, int n) {
    __shared__ unsigned wsum[16];
    int tid = threadIdx.x, lane = tid & 63, w = tid >> 6;
    unsigned carry = 0;
    for (int base = 0; base < n; base += 1024) {
        int i = base + tid;
        unsigned v = (i < n) ? cnt[i] : 0u;
        unsigned s = v;
        #pragma unroll
        for (int off = 1; off < 64; off <<= 1) {
            unsigned t = __shfl_up(s, off);
            if (lane >= off) s += t;
        }
        if (lane == 63) wsum[w] = s;
        __syncthreads();
        if (tid < 16) {
            unsigned t = wsum[tid];
            #pragma unroll
            for (int off = 1; off < 16; off <<= 1) {
                unsigned u = __shfl_up(t, off);
                if (tid >= off) t += u;
            }
            wsum[tid] = t;
        }
        __syncthreads();
        unsigned woff = (w == 0) ? 0u : wsum[w - 1];
        if (i < n) cur[i] = carry + woff + s - v;
        unsigned tot = wsum[15];
        __syncthreads();
        carry += tot;
    }
}

__global__ void scatter_k(const int* __restrict__ ei, const float* __restrict__ ea,
                          unsigned* __restrict__ cur,
                          int* __restrict__ srcS, int* __restrict__ dstS,
                          float* __restrict__ eaS, int E) {
    int e = blockIdx.x * 256 + threadIdx.x;
    if (e >= E) return;
    int d = ei[E + e];
    unsigned pos = atomicAdd(&cur[d], 1u);
    srcS[pos] = ei[e];
    dstS[pos] = d;
    eaS[(size_t)pos * 3 + 0] = ea[(size_t)e * 3 + 0];
    eaS[(size_t)pos * 3 + 1] = ea[(size_t)e * 3 + 1];
    eaS[(size_t)pos * 3 + 2] = ea[(size_t)e * 3 + 2];
}

// ---------------- Edge kernel: round-2 structure verbatim (64 edges/block, 4 waves x M=16) ----
// Consumes (srcA,dstA,eaA) which are either raw inputs or dst-sorted copies.
__global__ __launch_bounds__(256, 4)
void edge_mfma(const unsigned short* __restrict__ xb,   // [N][128] bf16
               const int* __restrict__ srcA,            // [E]
               const int* __restrict__ dstA,            // [E]
               const float* __restrict__ eaA,           // [E][3]
               const unsigned short* __restrict__ W1f,  // [8][8][64][8] bf16
               const unsigned short* __restrict__ W2f,  // [4][8][64][8] bf16
               const float* __restrict__ W1tail,        // [3][128] fp32
               const float* __restrict__ bm1,
               const float* __restrict__ bm2,
               float* __restrict__ agg,
               int E)
{
    __shared__ alignas(16) unsigned short As[4 * 4096]; // per wave: 16 rows x 512 B (swizzled)
    __shared__ float sW1e[3 * 128];
    __shared__ float sB1[128], sB2[128];
    __shared__ int   sIdx[4][32];   // [0:16) src, [16:32) dst
    __shared__ float sEA[4][48];

    const int tid  = threadIdx.x;
    const int lane = tid & 63;
    const int w    = tid >> 6;
    const int e0w  = blockIdx.x * 64 + w * 16;

    if (tid < 128) {
        sW1e[tid]       = W1tail[tid];
        sW1e[128 + tid] = W1tail[128 + tid];
        sW1e[256 + tid] = W1tail[256 + tid];
        sB1[tid] = bm1[tid];
        sB2[tid] = bm2[tid];
    }
    if (lane < 32) {
        int e = e0w + (lane & 15);
        sIdx[w][lane] = (e < E) ? ((lane < 16) ? srcA[e] : dstA[e]) : 0;
    }
    if (lane < 48) {
        size_t b = (size_t)e0w * 3 + lane;
        sEA[w][lane] = (b < (size_t)E * 3) ? eaA[b] : 0.f;
    }

    char* Aw = (char*)As + w * 8192;

    // gather [x_src | x_dst] bf16 rows into swizzled LDS (rows of 512 B; slot ^= row)
    #pragma unroll
    for (int it = 0; it < 8; ++it) {
        int g = it * 64 + lane;
        int r = g >> 4, c = g & 15;
        int e = r & 15, half = r >> 4;
        int node = sIdx[w][half * 16 + e];
        uint4 v = *(const uint4*)(xb + (size_t)node * 128 + c * 8);
        int b = half * 256 + c * 16;
        *(uint4*)(Aw + e * 512 + (b ^ (e << 4))) = v;
    }
    __syncthreads();

    const int arow = lane & 15;
    const int kgrp = (lane >> 4) << 4;   // byte offset of this lane's k-subgroup
    const int rbase = (lane >> 4) * 4;   // D-rows held by this lane

    // ---- GEMM1: [16,256]bf16 @ [256,128]bf16, fp32 acc ----
    f32x4 acc[8];
    #pragma unroll
    for (int i = 0; i < 8; ++i) acc[i] = (f32x4)0.f;

    #pragma unroll
    for (int ks = 0; ks < 8; ++ks) {
        short8 af = *(const short8*)(Aw + arow * 512 + ((ks * 64 + kgrp) ^ (arow << 4)));
        #pragma unroll
        for (int nt = 0; nt < 8; ++nt) {
            short8 bf = *(const short8*)(W1f + (size_t)((ks * 8 + nt) * 64 + lane) * 8);
            acc[nt] = __builtin_amdgcn_mfma_f32_16x16x32_bf16(af, bf, acc[nt], 0, 0, 0);
        }
    }

    // ---- epilogue 1: + edge_attr (exact fp32) + bias, relu, store H bf16 (swizzled, reuse A) ----
    float a0[4], a1[4], a2[4];
    #pragma unroll
    for (int r = 0; r < 4; ++r) {
        int e = rbase + r;
        a0[r] = sEA[w][e * 3 + 0];
        a1[r] = sEA[w][e * 3 + 1];
        a2[r] = sEA[w][e * 3 + 2];
    }
    #pragma unroll
    for (int nt = 0; nt < 8; ++nt) {
        int col = (nt << 4) + (lane & 15);
        float w0 = sW1e[col], w1 = sW1e[128 + col], w2 = sW1e[256 + col];
        float bb = sB1[col];
        #pragma unroll
        for (int r = 0; r < 4; ++r) {
            float h = acc[nt][r] + bb;
            h = fmaf(a0[r], w0, h);
            h = fmaf(a1[r], w1, h);
            h = fmaf(a2[r], w2, h);
            h = fmaxf(h, 0.f);
            int e = rbase + r;
            *(unsigned short*)(Aw + e * 256 + ((col * 2) ^ (e << 4))) = f2bf(h);
        }
    }
    __syncthreads();

    // ---- GEMM2: H[16,128]bf16 @ [128,128]bf16 ----
    #pragma unroll
    for (int i = 0; i < 8; ++i) acc[i] = (f32x4)0.f;
    #pragma unroll
    for (int ks = 0; ks < 4; ++ks) {
        short8 af = *(const short8*)(Aw + arow * 256 + ((ks * 64 + kgrp) ^ (arow << 4)));
        #pragma unroll
        for (int nt = 0; nt < 8; ++nt) {
            short8 bf = *(const short8*)(W2f + (size_t)((ks * 8 + nt) * 64 + lane) * 8);
            acc[nt] = __builtin_amdgcn_mfma_f32_16x16x32_bf16(af, bf, acc[nt], 0, 0, 0);
        }
    }

    // ---- epilogue 2: + bias, run-merged atomic scatter-add into agg[dst] ----
    // lane holds 4 consecutive edges (rows rbase..rbase+3); with dst-sorted input
    // these usually share the same dst -> merge before the atomic.
    int dstr[4];
    #pragma unroll
    for (int r = 0; r < 4; ++r) dstr[r] = sIdx[w][16 + rbase + r];

    #pragma unroll
    for (int nt = 0; nt < 8; ++nt) {
        int col = (nt << 4) + (lane & 15);
        float bb = sB2[col];
        float carry = 0.f;
        int   cd    = -1;
        #pragma unroll
        for (int r = 0; r < 4; ++r) {
            int eg = e0w + rbase + r;
            if (eg < E) {
                float v = acc[nt][r] + bb;
                if (dstr[r] == cd) {
                    carry += v;
                } else {
                    if (cd >= 0) unsafeAtomicAdd(agg + (size_t)cd * 128 + col, carry);
                    cd = dstr[r];
                    carry = v;
                }
            }
        }
        if (cd >= 0) unsafeAtomicAdd(agg + (size_t)cd * 128 + col, carry);
    }
}

// ---------------- Node kernel: bf16 MFMA with hi/lo split (near-fp32) ----------------
__global__ __launch_bounds__(256, 3)
void node_mfma(const float* __restrict__ x,
               const float* __restrict__ agg,
               const unsigned short* __restrict__ WgH, const unsigned short* __restrict__ WgL,
               const unsigned short* __restrict__ Wu1H, const unsigned short* __restrict__ Wu1L,
               const unsigned short* __restrict__ Wu2H, const unsigned short* __restrict__ Wu2L,
               const float* __restrict__ bg, const float* __restrict__ bu1,
               const float* __restrict__ bu2,
               const float* __restrict__ gamma, const float* __restrict__ beta,
               float* __restrict__ out, int N)
{
    __shared__ alignas(16) char Hs[4][8192];   // per-wave u1 hi/lo packed: 16 rows x 512 B

    const int tid  = threadIdx.x;
    const int lane = tid & 63;
    const int wid  = tid >> 6;
    const int n0   = (blockIdx.x * 4 + wid) * 16;
    if (n0 >= N) return;

    const int arow = lane & 15;
    const int g4   = lane >> 4;

    int nr = n0 + arow; if (nr >= N) nr = N - 1;
    const float* px = x   + (size_t)nr * 128 + g4 * 8;
    const float* pa = agg + (size_t)nr * 128 + g4 * 8;

    // ---- build A-frags (hi/lo) for [x | agg], K = 256 ----
    short8 ah[8], al[8];
    #pragma unroll
    for (int ks = 0; ks < 8; ++ks) {
        const float* p = (ks < 4) ? (px + ks * 32) : (pa + (ks - 4) * 32);
        float4 v0 = *(const float4*)p;
        float4 v1 = *(const float4*)(p + 4);
        float v[8] = { v0.x, v0.y, v0.z, v0.w, v1.x, v1.y, v1.z, v1.w };
        #pragma unroll
        for (int j = 0; j < 8; ++j) {
            unsigned short h = f2bf(v[j]);
            ah[ks][j] = (short)h;
            al[ks][j] = (short)f2bf(v[j] - bf2f(h));
        }
    }

    // ---- gate GEMM (K=256, 3-pass split) ----
    f32x4 ga[8];
    #pragma unroll
    for (int i = 0; i < 8; ++i) ga[i] = (f32x4)0.f;
    #pragma unroll
    for (int ks = 0; ks < 8; ++ks) {
        #pragma unroll
        for (int nt = 0; nt < 8; ++nt) {
            size_t o = (size_t)((ks * 8 + nt) * 64 + lane) * 8;
            short8 bh = *(const short8*)(WgH + o);
            short8 bl = *(const short8*)(WgL + o);
            ga[nt] = __builtin_amdgcn_mfma_f32_16x16x32_bf16(ah[ks], bh, ga[nt], 0, 0, 0);
            ga[nt] = __builtin_amdgcn_mfma_f32_16x16x32_bf16(al[ks], bh, ga[nt], 0, 0, 0);
            ga[nt] = __builtin_amdgcn_mfma_f32_16x16x32_bf16(ah[ks], bl, ga[nt], 0, 0, 0);
        }
    }

    // ---- u1 GEMM (K=256, 3-pass split) ----
    f32x4 ua[8];
    #pragma unroll
    for (int i = 0; i < 8; ++i) ua[i] = (f32x4)0.f;
    #pragma unroll
    for (int ks = 0; ks < 8; ++ks) {
        #pragma unroll
        for (int nt = 0; nt < 8; ++nt) {
            size_t o = (size_t)((ks * 8 + nt) * 64 + lane) * 8;
            short8 bh = *(const short8*)(Wu1H + o);
            short8 bl = *(const short8*)(Wu1L + o);
            ua[nt] = __builtin_amdgcn_mfma_f32_16x16x32_bf16(ah[ks], bh, ua[nt], 0, 0, 0);
            ua[nt] = __builtin_amdgcn_mfma_f32_16x16x32_bf16(al[ks], bh, ua[nt], 0, 0, 0);
            ua[nt] = __builtin_amdgcn_mfma_f32_16x16x32_bf16(ah[ks], bl, ua[nt], 0, 0, 0);
        }
    }

    // relu + bias, split hi/lo, pack (hi|lo<<16) into wave-private LDS (transpose)
    #pragma unroll
    for (int nt = 0; nt < 8; ++nt) {
        int col = nt * 16 + arow;
        float b1 = bu1[col];
        #pragma unroll
        for (int r = 0; r < 4; ++r) {
            int row = g4 * 4 + r;
            float u = fmaxf(ua[nt][r] + b1, 0.f);
            unsigned short h = f2bf(u);
            unsigned short l = f2bf(u - bf2f(h));
            unsigned int pk = (unsigned int)h | ((unsigned int)l << 16);
            *(unsigned int*)(&Hs[wid][row * 512 + ((col * 4) ^ ((row & 15) << 4))]) = pk;
        }
    }

    // ---- gate finalize: sigmoid ----
    #pragma unroll
    for (int nt = 0; nt < 8; ++nt) {
        int col = nt * 16 + arow;
        float b = bg[col];
        #pragma unroll
        for (int r = 0; r < 4; ++r)
            ga[nt][r] = 1.f / (1.f + expf(-(ga[nt][r] + b)));
    }
    __syncthreads();

    // ---- u2 GEMM (K=128, 3-pass split), A from LDS ----
    f32x4 u2[8];
    #pragma unroll
    for (int i = 0; i < 8; ++i) u2[i] = (f32x4)0.f;
    #pragma unroll
    for (int ks = 0; ks < 4; ++ks) {
        int b0 = ks * 128 + g4 * 32;
        unsigned int q0[4], q1[4];
        *(uint4*)q0 = *(const uint4*)(&Hs[wid][arow * 512 + ( b0       ^ (arow << 4))]);
        *(uint4*)q1 = *(const uint4*)(&Hs[wid][arow * 512 + ((b0 + 16) ^ (arow << 4))]);
        short8 a2h, a2l;
        #pragma unroll
        for (int j = 0; j < 4; ++j) {
            a2h[j]     = (short)(q0[j] & 0xffff);
            a2l[j]     = (short)(q0[j] >> 16);
            a2h[4 + j] = (short)(q1[j] & 0xffff);
            a2l[4 + j] = (short)(q1[j] >> 16);
        }
        #pragma unroll
        for (int nt = 0; nt < 8; ++nt) {
            size_t o = (size_t)((ks * 8 + nt) * 64 + lane) * 8;
            short8 bh = *(const short8*)(Wu2H + o);
            short8 bl = *(const short8*)(Wu2L + o);
            u2[nt] = __builtin_amdgcn_mfma_f32_16x16x32_bf16(a2h, bh, u2[nt], 0, 0, 0);
            u2[nt] = __builtin_amdgcn_mfma_f32_16x16x32_bf16(a2l, bh, u2[nt], 0, 0, 0);
            u2[nt] = __builtin_amdgcn_mfma_f32_16x16x32_bf16(a2h, bl, u2[nt], 0, 0, 0);
        }
    }

    // ---- epilogue: gating + LayerNorm + store ----
    float s[4]  = {0.f, 0.f, 0.f, 0.f};
    float ss[4] = {0.f, 0.f, 0.f, 0.f};
    #pragma unroll
    for (int nt = 0; nt < 8; ++nt) {
        int col = nt * 16 + arow;
        float b2 = bu2[col];
        #pragma unroll
        for (int r = 0; r < 4; ++r) {
            int node = n0 + g4 * 4 + r;
            float xv = x[(size_t)node * 128 + col];
            float g  = ga[nt][r];
            float o  = g * (u2[nt][r] + b2) + (1.f - g) * xv;
            u2[nt][r] = o;
            s[r]  += o;
            ss[r] += o * o;
        }
    }
    #pragma unroll
    for (int off = 8; off >= 1; off >>= 1) {
        #pragma unroll
        for (int r = 0; r < 4; ++r) {
            s[r]  += __shfl_xor(s[r],  off);
            ss[r] += __shfl_xor(ss[r], off);
        }
    }
    float mu[4], rstd[4];
    #pragma unroll
    for (int r = 0; r < 4; ++r) {
        mu[r] = s[r] * (1.f / 128.f);
        float var = ss[r] * (1.f / 128.f) - mu[r] * mu[r];
        rstd[r] = rsqrtf(var + 1e-5f);
    }
    #pragma unroll
    for (int nt = 0; nt < 8; ++nt) {
        int col = nt * 16 + arow;
        float gm = gamma[col], bt = beta[col];
        #pragma unroll
        for (int r = 0; r < 4; ++r) {
            int node = n0 + g4 * 4 + r;
            if (node < N)
                out[(size_t)node * 128 + col] = (u2[nt][r] - mu[r]) * rstd[r] * gm + bt;
        }
    }
}

extern "C" void kernel_launch(void* const* d_in, const int* in_sizes, int n_in,
                              void* d_out, int out_size, void* d_ws, size_t ws_size,
                              hipStream_t stream)
{
    const float* x    = (const float*)d_in[0];
    const int*   ei   = (const int*)  d_in[1];
    const float* ea   = (const float*)d_in[2];
    const float* Wm1  = (const float*)d_in[3];
    const float* bm1  = (const float*)d_in[4];
    const float* Wm2  = (const float*)d_in[5];
    const float* bm2  = (const float*)d_in[6];
    const float* Wg   = (const float*)d_in[7];
    const float* bg   = (const float*)d_in[8];
    const float* Wu1  = (const float*)d_in[9];
    const float* bu1  = (const float*)d_in[10];
    const float* Wu2  = (const float*)d_in[11];
    const float* bu2  = (const float*)d_in[12];
    const float* gmma = (const float*)d_in[13];
    const float* beta = (const float*)d_in[14];
    float* out = (float*)d_out;

    const int N = in_sizes[0] / HID;
    const int E = in_sizes[1] / 2;

    // workspace carve-up
    float*          agg  = (float*)d_ws;                             // N*128 f32
    unsigned short* xb   = (unsigned short*)(agg + (size_t)N * HID); // N*128 bf16
    unsigned short* W1f  = xb + (size_t)N * HID;                     // 32768
    unsigned short* W2f  = W1f + 32768;                              // 16384
    unsigned short* WgH  = W2f + 16384;
    unsigned short* WgL  = WgH + 32768;
    unsigned short* Wu1H = WgL + 32768;
    unsigned short* Wu1L = Wu1H + 32768;
    unsigned short* Wu2H = Wu1L + 32768;
    unsigned short* Wu2L = Wu2H + 16384;
    // sort scratch (only used if ws_size permits)
    unsigned* cnt  = (unsigned*)(Wu2L + 16384);   // N counters
    unsigned* cur  = cnt + N;                     // N cursors
    int*      srcS = (int*)(cur + N);             // E
    int*      dstS = srcS + E;                    // E
    float*    eaS  = (float*)(dstS + E);          // E*3
    size_t need = (size_t)((char*)(eaS + (size_t)E * 3) - (char*)d_ws);
    const bool do_sort = (ws_size >= need);

    hipMemsetAsync(agg, 0, (size_t)N * HID * sizeof(float), stream);

    int n4 = N * HID / 4;
    prep_x<<<dim3((n4 + 255) / 256), dim3(256), 0, stream>>>((const float4*)x, xb, n4);
    prep_w<<<dim3(16), dim3(256), 0, stream>>>(Wm1, W1f, 8);
    prep_w<<<dim3(8),  dim3(256), 0, stream>>>(Wm2, W2f, 4);
    prep_w_split<<<dim3(16), dim3(256), 0, stream>>>(Wg,  WgH,  WgL,  8);
    prep_w_split<<<dim3(16), dim3(256), 0, stream>>>(Wu1, Wu1H, Wu1L, 8);
    prep_w_split<<<dim3(8),  dim3(256), 0, stream>>>(Wu2, Wu2H, Wu2L, 4);

    const int*   srcA = ei;
    const int*   dstA = ei + E;
    const float* eaA  = ea;
    if (do_sort) {
        hipMemsetAsync(cnt, 0, (size_t)N * sizeof(unsigned), stream);
        hist_k<<<dim3((E + 255) / 256), dim3(256), 0, stream>>>(ei, cnt, E);
        scan_k<<<dim3(1), dim3(1024), 0, stream>>>(cnt, cur, N);
        scatter_k<<<dim3((E + 255) / 256), dim3(256), 0, stream>>>(ei, ea, cur, srcS, dstS, eaS, E);
        srcA = srcS; dstA = dstS; eaA = eaS;
    }

    edge_mfma<<<dim3((E + 63) / 64), dim3(256), 0, stream>>>(
        xb, srcA, dstA, eaA, W1f, W2f, Wm1 + 256 * HID, bm1, bm2, agg, E);

    int ntiles = (N + 15) / 16;
    node_mfma<<<dim3((ntiles + 3) / 4), dim3(256), 0, stream>>>(
        x, agg, WgH, WgL, Wu1H, Wu1L, Wu2H, Wu2L,
        bg, bu1, bu2, gmma, beta, out, N);
}